// Round 3
// baseline (109.093 us; speedup 1.0000x reference)
//
#include <hip/hip_runtime.h>

#define B_  16
#define LQ  256
#define LK  256
#define QD  256
#define HD  128
#define VD  128

// 2*log2(e): exp2(SCALE2*x) = e^{2x}
#define SCALE2 2.8853900817779268f
#define L2E    1.4426950408889634f
#define CTX_SIZE (B_ * LK * VD)

__device__ __forceinline__ float fast_exp2(float x) { return __builtin_amdgcn_exp2f(x); }
__device__ __forceinline__ float fast_rcp(float x)  { return __builtin_amdgcn_rcpf(x); }

// ---------------------------------------------------------------------------
// proj_kernel: 1024 blocks x 256 threads. 8-row x 128-h tiles, split-K by wave.
//   blocks [0,512):    qe4[b][h4][q]  = exp2(SCALE2*(query@Wq)) as float4 over 4 h
//   blocks [512,1024): ke4[b][k][h4]  = exp2(SCALE2*(key@Wk))   row-major float4
// Both stores fully coalesced (float4, consecutive lanes consecutive addresses).
// ---------------------------------------------------------------------------
__global__ __launch_bounds__(256, 4) void proj_kernel(const float* __restrict__ query,
                                                      const float* __restrict__ key,
                                                      const float* __restrict__ Wq,
                                                      const float* __restrict__ Wk,
                                                      float4* __restrict__ qe4,
                                                      float4* __restrict__ ke4)
{
    __shared__ float  Xs[8][258];        // 8 rows x K=256, pad 2 (8B-aligned rows)
    __shared__ float4 part[4][32][9];    // [wave][hg][m] padded m-dim -> conflict-free

    const int t = threadIdx.x;
    const bool isQ = (blockIdx.x < 512);
    const int blk  = isQ ? blockIdx.x : (blockIdx.x - 512);
    const int rows0 = blk * 8;
    const float* X = isQ ? query : key;
    const float4* W4 = (const float4*)(isQ ? Wq : Wk);   // [k][32] float4 over h

    // ---- stage X tile: 8 rows x 256 k ----
    {
        const int r = t >> 5;            // 0..7
        const int c = (t & 31) * 8;      // 0..248
        const float4 x0 = *(const float4*)(X + (size_t)(rows0 + r) * QD + c);
        const float4 x1 = *(const float4*)(X + (size_t)(rows0 + r) * QD + c + 4);
        *(float4*)&Xs[r][c]     = x0;
        *(float4*)&Xs[r][c + 4] = x1;
    }
    __syncthreads();

    const int w    = t >> 6;
    const int lane = t & 63;
    const int hg   = lane & 31;          // h4 index (h = hg*4 .. hg*4+3)
    const int mb   = lane >> 5;          // half-wave covers m = mb, mb+2, mb+4, mb+6

    float4 acc[4];
#pragma unroll
    for (int i = 0; i < 4; i++) acc[i] = make_float4(0.f, 0.f, 0.f, 0.f);

    const int kbase = w * 64;
#pragma unroll 4
    for (int kk = 0; kk < 64; kk += 2) {
        const int k = kbase + kk;
        const float4 w0 = W4[(size_t)k * 32 + hg];
        const float4 w1 = W4[(size_t)(k + 1) * 32 + hg];
#pragma unroll
        for (int mi = 0; mi < 4; mi++) {
            const float2 x = *(const float2*)&Xs[mb + 2 * mi][k];
            acc[mi].x += x.x * w0.x + x.y * w1.x;
            acc[mi].y += x.x * w0.y + x.y * w1.y;
            acc[mi].z += x.x * w0.z + x.y * w1.z;
            acc[mi].w += x.x * w0.w + x.y * w1.w;
        }
    }
#pragma unroll
    for (int mi = 0; mi < 4; mi++) part[w][hg][mb + 2 * mi] = acc[mi];
    __syncthreads();

    // ---- reduce 4 split-K partials, exp, coalesced store ----
    if (isQ) {
        const int q8 = t & 7, h4 = t >> 3;    // lanes: q fastest -> coalesced
        float4 s = part[0][h4][q8];
        const float4 p1 = part[1][h4][q8];
        const float4 p2 = part[2][h4][q8];
        const float4 p3 = part[3][h4][q8];
        s.x += p1.x + p2.x + p3.x;  s.y += p1.y + p2.y + p3.y;
        s.z += p1.z + p2.z + p3.z;  s.w += p1.w + p2.w + p3.w;
        const float4 e = make_float4(fast_exp2(s.x * SCALE2), fast_exp2(s.y * SCALE2),
                                     fast_exp2(s.z * SCALE2), fast_exp2(s.w * SCALE2));
        const int row = rows0 + q8, b = row >> 8, q = row & 255;
        qe4[((size_t)b * 32 + h4) * 256 + q] = e;
    } else {
        const int h4 = t & 31, m = t >> 5;    // lanes: h fastest -> coalesced
        float4 s = part[0][h4][m];
        const float4 p1 = part[1][h4][m];
        const float4 p2 = part[2][h4][m];
        const float4 p3 = part[3][h4][m];
        s.x += p1.x + p2.x + p3.x;  s.y += p1.y + p2.y + p3.y;
        s.z += p1.z + p2.z + p3.z;  s.w += p1.w + p2.w + p3.w;
        const float4 e = make_float4(fast_exp2(s.x * SCALE2), fast_exp2(s.y * SCALE2),
                                     fast_exp2(s.z * SCALE2), fast_exp2(s.w * SCALE2));
        ke4[(size_t)(rows0 + m) * 32 + h4] = e;
    }
}

// ---------------------------------------------------------------------------
// attn_kernel: 1024 blocks x 256 threads. Block = (b, 4 consecutive k).
// Phase 1: thread=q, float4 qe loads: score[k][q] = sumv - 2*sum_h v*rcp(1+qe*ke)
// Phase 2: wave w -> softmax over q for k=w
// Phase 3: wave w -> q-range, all 4 k, LDS partial reduce -> context
// ---------------------------------------------------------------------------
__global__ __launch_bounds__(256, 4) void attn_kernel(const float4* __restrict__ qe4,
                                                      const float4* __restrict__ ke4,
                                                      const float* __restrict__ v,
                                                      const float* __restrict__ value,
                                                      float* __restrict__ out)
{
    __shared__ float  score_s[4][260];
    __shared__ float  attn_T[256][4];
    __shared__ float2 partc[4][4][64];

    const int t  = threadIdx.x;
    const int b  = blockIdx.x >> 6;
    const int k0 = (blockIdx.x & 63) << 2;

    const float4* qb = qe4 + (size_t)b * 32 * 256;           // [h4][q]
    const float4* kb = ke4 + ((size_t)b * LK + k0) * 32;     // 4 rows x 32 float4
    const float4* v4 = (const float4*)v;

    // ---- Phase 1 ----
    float acc0 = 0.f, acc1 = 0.f, acc2 = 0.f, acc3 = 0.f;
    const int q = t;
#pragma unroll 4
    for (int h4 = 0; h4 < 32; h4++) {
        const float4 qv = qb[(size_t)h4 * 256 + q];
        const float4 vv = v4[h4];
        const float4 ka = kb[0 * 32 + h4];
        const float4 kc = kb[1 * 32 + h4];
        const float4 kd = kb[2 * 32 + h4];
        const float4 kf = kb[3 * 32 + h4];
        acc0 += vv.x * fast_rcp(qv.x * ka.x + 1.f) + vv.y * fast_rcp(qv.y * ka.y + 1.f)
              + vv.z * fast_rcp(qv.z * ka.z + 1.f) + vv.w * fast_rcp(qv.w * ka.w + 1.f);
        acc1 += vv.x * fast_rcp(qv.x * kc.x + 1.f) + vv.y * fast_rcp(qv.y * kc.y + 1.f)
              + vv.z * fast_rcp(qv.z * kc.z + 1.f) + vv.w * fast_rcp(qv.w * kc.w + 1.f);
        acc2 += vv.x * fast_rcp(qv.x * kd.x + 1.f) + vv.y * fast_rcp(qv.y * kd.y + 1.f)
              + vv.z * fast_rcp(qv.z * kd.z + 1.f) + vv.w * fast_rcp(qv.w * kd.w + 1.f);
        acc3 += vv.x * fast_rcp(qv.x * kf.x + 1.f) + vv.y * fast_rcp(qv.y * kf.y + 1.f)
              + vv.z * fast_rcp(qv.z * kf.z + 1.f) + vv.w * fast_rcp(qv.w * kf.w + 1.f);
    }
    float sumv = 0.f;  // wave-uniform (scalar pipe)
#pragma unroll
    for (int h4 = 0; h4 < 32; h4++) {
        const float4 vv = v4[h4];
        sumv += vv.x + vv.y + vv.z + vv.w;
    }

    score_s[0][q] = sumv - 2.f * acc0;
    score_s[1][q] = sumv - 2.f * acc1;
    score_s[2][q] = sumv - 2.f * acc2;
    score_s[3][q] = sumv - 2.f * acc3;
    __syncthreads();

    // ---- Phase 2: softmax over q, wave w -> k=w ----
    const int w = t >> 6, lane = t & 63;
    {
        float x0 = score_s[w][lane];
        float x1 = score_s[w][lane + 64];
        float x2 = score_s[w][lane + 128];
        float x3 = score_s[w][lane + 192];
        float m = fmaxf(fmaxf(x0, x1), fmaxf(x2, x3));
#pragma unroll
        for (int off = 32; off >= 1; off >>= 1) m = fmaxf(m, __shfl_xor(m, off));
        float e0 = fast_exp2((x0 - m) * L2E);
        float e1 = fast_exp2((x1 - m) * L2E);
        float e2 = fast_exp2((x2 - m) * L2E);
        float e3 = fast_exp2((x3 - m) * L2E);
        float s = e0 + e1 + e2 + e3;
#pragma unroll
        for (int off = 32; off >= 1; off >>= 1) s += __shfl_xor(s, off);
        const float rs = fast_rcp(s);
        e0 *= rs; e1 *= rs; e2 *= rs; e3 *= rs;
        attn_T[lane][w]       = e0;
        attn_T[lane + 64][w]  = e1;
        attn_T[lane + 128][w] = e2;
        attn_T[lane + 192][w] = e3;
        float* ao = out + CTX_SIZE + ((size_t)(b * LK + k0 + w)) * LQ;
        ao[lane]       = e0;
        ao[lane + 64]  = e1;
        ao[lane + 128] = e2;
        ao[lane + 192] = e3;
    }
    __syncthreads();

    // ---- Phase 3: context ----
    {
        const int vd2 = lane * 2;
        const float* valb = value + (size_t)b * LQ * VD;
        float2 c0 = {0.f, 0.f}, c1 = {0.f, 0.f}, c2 = {0.f, 0.f}, c3 = {0.f, 0.f};
#pragma unroll 4
        for (int i = 0; i < 64; i++) {
            const int q2 = (w << 6) + i;
            const float4 a = *(const float4*)&attn_T[q2][0];
            const float2 vv = *(const float2*)(valb + (size_t)q2 * VD + vd2);
            c0.x += a.x * vv.x; c0.y += a.x * vv.y;
            c1.x += a.y * vv.x; c1.y += a.y * vv.y;
            c2.x += a.z * vv.x; c2.y += a.z * vv.y;
            c3.x += a.w * vv.x; c3.y += a.w * vv.y;
        }
        partc[w][0][lane] = c0;
        partc[w][1][lane] = c1;
        partc[w][2][lane] = c2;
        partc[w][3][lane] = c3;
    }
    __syncthreads();
    {
        const int kg = t >> 6, l2 = t & 63;
        const float2 p0 = partc[0][kg][l2];
        const float2 p1 = partc[1][kg][l2];
        const float2 p2 = partc[2][kg][l2];
        const float2 p3 = partc[3][kg][l2];
        float2 s;
        s.x = p0.x + p1.x + p2.x + p3.x;
        s.y = p0.y + p1.y + p2.y + p3.y;
        *(float2*)(out + ((size_t)(b * LK + k0 + kg)) * VD + l2 * 2) = s;
    }
}

extern "C" void kernel_launch(void* const* d_in, const int* in_sizes, int n_in,
                              void* d_out, int out_size, void* d_ws, size_t ws_size,
                              hipStream_t stream)
{
    const float* query = (const float*)d_in[0];
    const float* key   = (const float*)d_in[1];
    const float* value = (const float*)d_in[2];
    const float* Wq    = (const float*)d_in[3];
    const float* Wk    = (const float*)d_in[4];
    const float* v     = (const float*)d_in[5];
    float* out = (float*)d_out;

    float4* qe4 = (float4*)d_ws;                         // [B][32][256] float4
    float4* ke4 = qe4 + (size_t)B_ * 32 * 256;           // [B][256][32] float4

    proj_kernel<<<dim3(1024), 256, 0, stream>>>(query, key, Wq, Wk, qe4, ke4);
    attn_kernel<<<dim3(1024), 256, 0, stream>>>(qe4, ke4, v, value, out);
}